// Round 7
// baseline (843.891 us; speedup 1.0000x reference)
//
#include <hip/hip_runtime.h>
#include <math.h>

typedef __bf16 bf16x8 __attribute__((ext_vector_type(8)));
typedef float f32x4 __attribute__((ext_vector_type(4)));
typedef unsigned short ushort8 __attribute__((ext_vector_type(8)));

__device__ __forceinline__ float bf2f(unsigned short u) {
  union { unsigned int i; float f; } c; c.i = ((unsigned int)u) << 16; return c.f;
}
__device__ __forceinline__ unsigned short f2bf(float f) {
  union { float f; unsigned int i; } c; c.f = f;
  unsigned int r = (c.i + 0x7fffu + ((c.i >> 16) & 1u)) >> 16;
  return (unsigned short)r;
}

// ---------------- init: zero all stat/bias buffers, deg = 1 (self loop) ----------------
__global__ void zero_k(float* __restrict__ statz, int nz, int* __restrict__ deg, int n) {
  int i = blockIdx.x * blockDim.x + threadIdx.x;
  if (i < nz) statz[i] = 0.f;
  if (i < n) deg[i] = 1;
}

__global__ void deg_count_k(const int* __restrict__ dst, int* __restrict__ deg, int e) {
  int i = blockIdx.x * blockDim.x + threadIdx.x;
  if (i < e) atomicAdd(&deg[dst[i]], 1);
}

__global__ void scan_k(const int* __restrict__ deg, int* __restrict__ offsets,
                       int* __restrict__ cursor, int n) {
  __shared__ int sums[1024];
  int tid = threadIdx.x;
  int chunk = (n + 1023) >> 10;
  int base = tid * chunk;
  int s = 0;
  for (int i = 0; i < chunk; ++i) {
    int j = base + i;
    if (j < n) s += deg[j];
  }
  sums[tid] = s;
  __syncthreads();
  for (int off = 1; off < 1024; off <<= 1) {
    int v = (tid >= off) ? sums[tid - off] : 0;
    __syncthreads();
    sums[tid] += v;
    __syncthreads();
  }
  int run = sums[tid] - s;
  for (int i = 0; i < chunk; ++i) {
    int j = base + i;
    if (j < n) {
      offsets[j] = run;
      cursor[j] = run;
      run += deg[j];
    }
  }
  if (tid == 1023) offsets[n] = sums[1023];
}

__global__ void csr_fill_k(const int* __restrict__ src, const int* __restrict__ dst,
                           int* __restrict__ cursor, int* __restrict__ csr_src,
                           int e, int n) {
  int i = blockIdx.x * blockDim.x + threadIdx.x;
  if (i >= e + n) return;
  int s, d;
  if (i < e) { s = src[i]; d = dst[i]; }
  else       { s = i - e;  d = s; }
  int pos = atomicAdd(&cursor[d], 1);
  csr_src[pos] = s;
}

// ---------------- fused BN0 stats + fp32->bf16 raw convert (coalesced) ----
__global__ __launch_bounds__(256)
void stats_convert_k(const float* __restrict__ x, unsigned short* __restrict__ Abf,
                     float* __restrict__ s1, float* __restrict__ s2,
                     int M, int K, int Kp) {
  int c = blockIdx.x * 256 + threadIdx.x;
  if (c >= Kp) return;
  int rows = (M + gridDim.y - 1) / gridDim.y;
  int r0 = blockIdx.y * rows;
  int r1 = min(M, r0 + rows);
  if (c >= K) {  // zero pad columns
    for (int r = r0; r < r1; ++r) Abf[(size_t)r * Kp + c] = 0;
    return;
  }
  float a = 0.f, b = 0.f;
  int r = r0;
  for (; r + 4 <= r1; r += 4) {
    float v0 = x[(size_t)(r + 0) * K + c];
    float v1 = x[(size_t)(r + 1) * K + c];
    float v2 = x[(size_t)(r + 2) * K + c];
    float v3 = x[(size_t)(r + 3) * K + c];
    a += v0 + v1 + v2 + v3;
    b += v0 * v0 + v1 * v1 + v2 * v2 + v3 * v3;
    Abf[(size_t)(r + 0) * Kp + c] = f2bf(v0);
    Abf[(size_t)(r + 1) * Kp + c] = f2bf(v1);
    Abf[(size_t)(r + 2) * Kp + c] = f2bf(v2);
    Abf[(size_t)(r + 3) * Kp + c] = f2bf(v3);
  }
  for (; r < r1; ++r) {
    float v = x[(size_t)r * K + c];
    a += v; b += v * v;
    Abf[(size_t)r * Kp + c] = f2bf(v);
  }
  atomicAdd(&s1[c], a);
  atomicAdd(&s2[c], b);
}

// ---------------- bf16 column stats ----------------
__global__ __launch_bounds__(256)
void col_stats_bf_k(const unsigned short* __restrict__ h, int M, int D,
                    float* __restrict__ s1, float* __restrict__ s2) {
  int c = blockIdx.x * 256 + threadIdx.x;
  if (c >= D) return;
  int rows = (M + gridDim.y - 1) / gridDim.y;
  int r0 = blockIdx.y * rows;
  int r1 = min(M, r0 + rows);
  float a = 0.f, b = 0.f;
  int r = r0;
  for (; r + 4 <= r1; r += 4) {
    float v0 = bf2f(h[(size_t)(r + 0) * D + c]);
    float v1 = bf2f(h[(size_t)(r + 1) * D + c]);
    float v2 = bf2f(h[(size_t)(r + 2) * D + c]);
    float v3 = bf2f(h[(size_t)(r + 3) * D + c]);
    a += v0 + v1 + v2 + v3;
    b += v0 * v0 + v1 * v1 + v2 * v2 + v3 * v3;
  }
  for (; r < r1; ++r) {
    float v = bf2f(h[(size_t)r * D + c]);
    a += v; b += v * v;
  }
  atomicAdd(&s1[c], a);
  atomicAdd(&s2[c], b);
}

// BN finalize + apply + ReLU fused, bf16 -> bf16, ushort8 vectorized
__global__ __launch_bounds__(256)
void bn_apply8_k(const unsigned short* __restrict__ h,
                 const float* __restrict__ s1, const float* __restrict__ s2,
                 const float* __restrict__ g, const float* __restrict__ b,
                 unsigned short* __restrict__ outb,
                 size_t total, int D, float invM) {
  size_t i = ((size_t)blockIdx.x * 256 + threadIdx.x) * 8;
  if (i >= total) return;
  ushort8 u = *(const ushort8*)(h + i);
  int c = (int)(i % (size_t)D);
  ushort8 o;
#pragma unroll
  for (int j = 0; j < 8; ++j) {
    float m = s1[c + j] * invM;
    float var = fmaxf(s2[c + j] * invM - m * m, 0.f);
    float a = rsqrtf(var + 1e-5f) * g[c + j];
    float cc = b[c + j] - m * a;
    float v = bf2f(u[j]) * a + cc;
    o[j] = f2bf(fmaxf(v, 0.f));
  }
  *(ushort8*)(outb + i) = o;
}

// weight transpose-convert for an l/r PAIR via blockIdx.z:
// W [K,N] fp32 -> WT[z*N .. ][N,Kp] bf16, zero pad.
// BN0-fold mode (s1 != nullptr): row k scaled by a[k]=rsqrt(var)*g, and
// bias[n] += sum_k c[k]*W[k,n] with c[k]=b[k]-m[k]*a[k] (computed inline from s1/s2).
__global__ __launch_bounds__(256)
void wconv_pair_k(const float* __restrict__ Wl, const float* __restrict__ Wr,
                  unsigned short* __restrict__ WT, int K, int N, int Kp,
                  const float* __restrict__ s1, const float* __restrict__ s2,
                  const float* __restrict__ gg, const float* __restrict__ bb,
                  float* __restrict__ bias, float invM) {
  const float* W = blockIdx.z ? Wr : Wl;
  unsigned short* WTo = WT + (size_t)blockIdx.z * N * Kp;
  __shared__ float t[32][33];
  int n0 = blockIdx.x * 32, k0 = blockIdx.y * 32;
  int tx = threadIdx.x & 31, ty = threadIdx.x >> 5;  // 32 x 8
  float bsum = 0.f;
#pragma unroll
  for (int i = 0; i < 32; i += 8) {
    int k = k0 + ty + i, nn = n0 + tx;
    float v = (k < K && nn < N) ? W[(size_t)k * N + nn] : 0.f;
    t[ty + i][tx] = v;
    if (s1 && k < K) {
      float m = s1[k] * invM;
      float var = fmaxf(s2[k] * invM - m * m, 0.f);
      float a = rsqrtf(var + 1e-5f) * gg[k];
      float c = bb[k] - m * a;
      bsum += c * v;
    }
  }
  if (s1) atomicAdd(&bias[blockIdx.z * N + n0 + tx], bsum);
  // per-thread output scale for k = k0 + tx
  float ascale = 1.f;
  if (s1) {
    int k = k0 + tx;
    if (k < K) {
      float m = s1[k] * invM;
      float var = fmaxf(s2[k] * invM - m * m, 0.f);
      ascale = rsqrtf(var + 1e-5f) * gg[k];
    }
  }
  __syncthreads();
#pragma unroll
  for (int i = 0; i < 32; i += 8) {
    int nn = n0 + ty + i, k = k0 + tx;
    if (nn < N && k < Kp) {
      float v = t[tx][ty + i] * ascale;
      WTo[(size_t)nn * Kp + k] = f2bf(v);
    }
  }
}

// ---------------- bf16 MFMA GEMM: C = A[M,K] @ Bt[Ntot,K]^T (+bias row), split store --
// XCD-aware swizzle: each XCD owns gridDim.x/8 column-tiles x all row-tiles, so its
// L2 holds a small B strip (<=1.7MB) while A streams (cross-XCD A re-reads hit L3).
__global__ __launch_bounds__(256)
void gemm_bf16_k(const unsigned short* __restrict__ A,
                 const unsigned short* __restrict__ Bt,
                 unsigned short* __restrict__ outL, unsigned short* __restrict__ outR,
                 const float* __restrict__ bias, int M, int Nh, int K) {
  __shared__ unsigned short sA[128 * 64];
  __shared__ unsigned short sB[128 * 64];
  const int tid = threadIdx.x;
  const int wave = tid >> 6, lane = tid & 63;
  const int wm = wave >> 1, wn = wave & 1;
  const int l16 = lane & 15, lq = lane >> 4;

  int ct, rt;
  {
    int bid = blockIdx.y * gridDim.x + blockIdx.x;
    int nb = gridDim.x * gridDim.y;
    if (((nb & 7) == 0) && ((gridDim.x & 7) == 0)) {
      int cpx = gridDim.x >> 3;       // col-tiles per XCD (power of 2 here)
      int xcd = bid & 7, j = bid >> 3;
      ct = xcd * cpx + (j & (cpx - 1));
      rt = j / cpx;
    } else {
      ct = blockIdx.x; rt = blockIdx.y;
    }
  }
  const int row0 = rt * 128, col0 = ct * 128;

  f32x4 acc[4][4] = {};

  for (int kt = 0; kt < K; kt += 64) {
#pragma unroll
    for (int i = 0; i < 4; ++i) {
      int s = i * 256 + tid;
      int r = s >> 3;
      int g = (s & 7) ^ (r & 7);
      int ra = row0 + r;
      ra = ra < M ? ra : M - 1;
      const unsigned short* ga = A + (size_t)ra * K + (kt + g * 8);
      __builtin_amdgcn_global_load_lds(
          (const __attribute__((address_space(1))) void*)ga,
          (__attribute__((address_space(3))) void*)&sA[s * 8], 16, 0, 0);
      const unsigned short* gb = Bt + (size_t)(col0 + r) * K + (kt + g * 8);
      __builtin_amdgcn_global_load_lds(
          (const __attribute__((address_space(1))) void*)gb,
          (__attribute__((address_space(3))) void*)&sB[s * 8], 16, 0, 0);
    }
    __syncthreads();
#pragma unroll
    for (int ks = 0; ks < 2; ++ks) {
      bf16x8 af[4], bff[4];
#pragma unroll
      for (int t = 0; t < 4; ++t) {
        int g = ks * 4 + lq;
        int r = wm * 64 + t * 16 + l16;
        af[t] = *(const bf16x8*)&sA[(r * 8 + (g ^ (r & 7))) * 8];
        int rb = wn * 64 + t * 16 + l16;
        bff[t] = *(const bf16x8*)&sB[(rb * 8 + (g ^ (rb & 7))) * 8];
      }
#pragma unroll
      for (int mt = 0; mt < 4; ++mt)
#pragma unroll
        for (int nt = 0; nt < 4; ++nt)
          acc[mt][nt] = __builtin_amdgcn_mfma_f32_16x16x32_bf16(af[mt], bff[nt], acc[mt][nt], 0, 0, 0);
    }
    __syncthreads();
  }
#pragma unroll
  for (int mt = 0; mt < 4; ++mt) {
    int rbase = row0 + wm * 64 + mt * 16 + lq * 4;
#pragma unroll
    for (int nt = 0; nt < 4; ++nt) {
      int col = col0 + wn * 64 + nt * 16 + l16;
      float bv = bias ? bias[col] : 0.f;
      unsigned short* base;
      int cc;
      if (col < Nh) { base = outL; cc = col; }
      else          { base = outR; cc = col - Nh; }
#pragma unroll
      for (int r = 0; r < 4; ++r) {
        int rr = rbase + r;
        if (rr < M) base[(size_t)rr * Nh + cc] = f2bf(acc[mt][nt][r] + bv);
      }
    }
  }
}

// ---------------- Fused GATv2 edge kernel, depth-3 pipelined gathers ----------------
template <int H>
__global__ __launch_bounds__(256)
void gat_edge_k(const unsigned short* __restrict__ xl, const unsigned short* __restrict__ xr,
                const float* __restrict__ att, const float* __restrict__ bias,
                const int* __restrict__ csr, const int* __restrict__ offsets,
                unsigned short* __restrict__ out, int n, int relu) {
  int gw = (blockIdx.x * 256 + threadIdx.x) >> 6;
  int lane = threadIdx.x & 63;
  if (gw >= n * H) return;
  int node, head;
  if (H == 1) { node = gw; head = 0; }
  else        { node = gw >> 1; head = gw & 1; }
  const int W = H * 512;
  const size_t rowoff = (size_t)node * W + head * 512;
  const size_t choff = (size_t)head * 512 + (size_t)(lane * 8);

  float xrv[8], atv[8];
  {
    ushort8 u = *(const ushort8*)(xr + rowoff + lane * 8);
    const float* ap = att + head * 512 + lane * 8;
#pragma unroll
    for (int j = 0; j < 8; ++j) { xrv[j] = bf2f(u[j]); atv[j] = ap[j]; }
  }
  int p0 = offsets[node], p1 = offsets[node + 1];
  ushort8 u0 = *(const ushort8*)(xl + (size_t)csr[p0] * W + choff);
  ushort8 u1 = u0, u2 = u0;
  if (p0 + 1 < p1) u1 = *(const ushort8*)(xl + (size_t)csr[p0 + 1] * W + choff);
  if (p0 + 2 < p1) u2 = *(const ushort8*)(xl + (size_t)csr[p0 + 2] * W + choff);

  float m = -1e30f, l = 0.f;
  float acc[8];
#pragma unroll
  for (int j = 0; j < 8; ++j) acc[j] = 0.f;
  for (int p = p0; p < p1; ++p) {
    ushort8 u = u0;
    u0 = u1; u1 = u2;
    if (p + 3 < p1) u2 = *(const ushort8*)(xl + (size_t)csr[p + 3] * W + choff);
    float lv[8];
    float e = 0.f;
#pragma unroll
    for (int j = 0; j < 8; ++j) {
      lv[j] = bf2f(u[j]);
      float z = lv[j] + xrv[j];
      z = fmaxf(z, 0.f) + 0.2f * fminf(z, 0.f);
      e = fmaf(z, atv[j], e);
    }
#pragma unroll
    for (int off = 32; off > 0; off >>= 1) e += __shfl_xor(e, off, 64);
    float mn = fmaxf(m, e);
    float corr = __expf(m - mn);
    float w = __expf(e - mn);
    l = l * corr + w;
#pragma unroll
    for (int j = 0; j < 8; ++j) acc[j] = acc[j] * corr + w * lv[j];
    m = mn;
  }
  float inv = 1.f / (l * (float)(p1 - p0));
  const float* bp = bias + head * 512 + lane * 8;
  ushort8 o;
#pragma unroll
  for (int j = 0; j < 8; ++j) {
    float v = acc[j] * inv + bp[j];
    if (relu) v = fmaxf(v, 0.f);
    o[j] = f2bf(v);
  }
  *(ushort8*)(out + rowoff + lane * 8) = o;
}

// ---------------- fused head + gather: out = sigmoid(h[tidx]@Wh+bh), y[tidx] --------
__global__ __launch_bounds__(256)
void head_gather_k(const unsigned short* __restrict__ h, const float* __restrict__ Wh,
                   const float* __restrict__ bh, const float* __restrict__ y,
                   const int* __restrict__ tidx, float* __restrict__ out, int nt) {
  int gw = (blockIdx.x * 256 + threadIdx.x) >> 6;
  int lane = threadIdx.x & 63;
  if (gw >= nt) return;
  int j = tidx[gw];
  ushort8 u = *(const ushort8*)(h + (size_t)j * 512 + lane * 8);
  const float* wp = Wh + lane * 8;
  float s = 0.f;
#pragma unroll
  for (int q = 0; q < 8; ++q) s = fmaf(bf2f(u[q]), wp[q], s);
#pragma unroll
  for (int off = 32; off > 0; off >>= 1) s += __shfl_xor(s, off, 64);
  if (lane == 0) {
    out[gw] = 1.f / (1.f + __expf(-(s + bh[0])));
    out[nt + gw] = y[j];
  }
}

// ---------------- launch ----------------
extern "C" void kernel_launch(void* const* d_in, const int* in_sizes, int n_in,
                              void* d_out, int out_size, void* d_ws, size_t ws_size,
                              hipStream_t stream) {
  const float* x     = (const float*)d_in[0];
  const int*   ei    = (const int*)d_in[1];
  const float* y     = (const float*)d_in[2];
  const int*   tidx  = (const int*)d_in[3];
  const float* bn0_g = (const float*)d_in[4];
  const float* bn0_b = (const float*)d_in[5];
  const float* W1l   = (const float*)d_in[6];
  const float* W1r   = (const float*)d_in[7];
  const float* a1    = (const float*)d_in[8];
  const float* b1    = (const float*)d_in[9];
  const float* bn1_g = (const float*)d_in[10];
  const float* bn1_b = (const float*)d_in[11];
  const float* W2l   = (const float*)d_in[12];
  const float* W2r   = (const float*)d_in[13];
  const float* a2    = (const float*)d_in[14];
  const float* b2    = (const float*)d_in[15];
  const float* bn2_g = (const float*)d_in[16];
  const float* bn2_b = (const float*)d_in[17];
  const float* W3l   = (const float*)d_in[18];
  const float* W3r   = (const float*)d_in[19];
  const float* a3    = (const float*)d_in[20];
  const float* b3    = (const float*)d_in[21];
  const float* bn3_g = (const float*)d_in[22];
  const float* bn3_b = (const float*)d_in[23];
  const float* W4l   = (const float*)d_in[24];
  const float* W4r   = (const float*)d_in[25];
  const float* a4    = (const float*)d_in[26];
  const float* b4    = (const float*)d_in[27];
  const float* Wh    = (const float*)d_in[28];
  const float* bh    = (const float*)d_in[29];
  float* out = (float*)d_out;

  const int n   = in_sizes[2];      // 8000
  const int E   = in_sizes[1] / 2;  // 64000
  const int FIN = in_sizes[4];      // 3201
  const int NT  = in_sizes[3];      // 4000
  const int ET  = E + n;
  const int KP1 = 3264;

  // ---- workspace layout ----
  unsigned short* us = (unsigned short*)d_ws;
  const size_t ABF_SZ = (size_t)n * KP1;
  unsigned short* Abf = us;
  unsigned short* hb  = us + ABF_SZ;
  unsigned short* xlb = hb + (size_t)n * 1024;
  unsigned short* xrb = xlb + (size_t)n * 1024;
  float* fp = (float*)(xrb + (size_t)n * 1024);
  // zeroed region: [s1_0|s2_0|s1_1|s2_1|s1_2|s2_2|s1_3|s2_3|biasb] = 14848 floats
  float* s1_0  = fp;           fp += 3328;
  float* s2_0  = fp;           fp += 3328;
  float* s1_1  = fp;           fp += 1024;
  float* s2_1  = fp;           fp += 1024;
  float* s1_2  = fp;           fp += 1024;
  float* s2_2  = fp;           fp += 1024;
  float* s1_3  = fp;           fp += 1024;
  float* s2_3  = fp;           fp += 1024;
  float* biasb = fp;           fp += 2048;
  const int kZeroCount = 14848;
  int* deg     = (int*)fp;
  int* offsets = deg + n;
  int* cursor  = offsets + n + 1;
  int* csr     = cursor + n;
  unsigned short* W1T = hb;                          // [2048, KP1] combined Bt
  unsigned short* WT  = Abf + (size_t)n * 1024;      // layers 2-4 combined Bt

  // ---- init + CSR build ----
  zero_k<<<(kZeroCount + 255) / 256, 256, 0, stream>>>(s1_0, kZeroCount, deg, n);
  deg_count_k<<<(E + 255) / 256, 256, 0, stream>>>(ei + E, deg, E);
  scan_k<<<1, 1024, 0, stream>>>(deg, offsets, cursor, n);
  csr_fill_k<<<(ET + 255) / 256, 256, 0, stream>>>(ei, ei + E, cursor, csr, E, n);

  float invM = 1.f / (float)n;

  // ---- BN0: fused stats + raw bf16 convert (single coalesced pass over x) ----
  {
    dim3 g((KP1 + 255) / 256, 200);
    stats_convert_k<<<g, 256, 0, stream>>>(x, Abf, s1_0, s2_0, n, FIN, KP1);
  }

  // ---- Layer 1 (H=2, K=3264 -> N=2048 combined), BN0 folded into weights ----
  {
    dim3 gw1(1024 / 32, KP1 / 32, 2);
    wconv_pair_k<<<gw1, 256, 0, stream>>>(W1l, W1r, W1T, FIN, 1024, KP1,
                                          s1_0, s2_0, bn0_g, bn0_b, biasb, invM);
    dim3 g(2048 / 128, (n + 127) / 128);
    gemm_bf16_k<<<g, 256, 0, stream>>>(Abf, W1T, xlb, xrb, biasb, n, 1024, KP1);
  }
  gat_edge_k<2><<<(n * 2 + 3) / 4, 256, 0, stream>>>(xlb, xrb, a1, b1, csr, offsets, hb, n, 0);
  {
    dim3 g(1024 / 256, 160);
    col_stats_bf_k<<<g, 256, 0, stream>>>(hb, n, 1024, s1_1, s2_1);
    bn_apply8_k<<<(int)(((size_t)n * 1024 / 8 + 255) / 256), 256, 0, stream>>>(
        hb, s1_1, s2_1, bn1_g, bn1_b, Abf, (size_t)n * 1024, 1024, invM);
  }

  // ---- Layer 2 (K=1024 -> N=1024 combined) ----
  {
    dim3 gw2(512 / 32, 1024 / 32, 2);
    wconv_pair_k<<<gw2, 256, 0, stream>>>(W2l, W2r, WT, 1024, 512, 1024,
                                          nullptr, nullptr, nullptr, nullptr, nullptr, 0.f);
    dim3 g(1024 / 128, (n + 127) / 128);
    gemm_bf16_k<<<g, 256, 0, stream>>>(Abf, WT, xlb, xrb, nullptr, n, 512, 1024);
  }
  gat_edge_k<1><<<(n + 3) / 4, 256, 0, stream>>>(xlb, xrb, a2, b2, csr, offsets, hb, n, 0);
  {
    dim3 g(512 / 256, 160);
    col_stats_bf_k<<<g, 256, 0, stream>>>(hb, n, 512, s1_2, s2_2);
    bn_apply8_k<<<(int)(((size_t)n * 512 / 8 + 255) / 256), 256, 0, stream>>>(
        hb, s1_2, s2_2, bn2_g, bn2_b, Abf, (size_t)n * 512, 512, invM);
  }

  // ---- Layer 3 (K=512 -> N=1024 combined) ----
  {
    dim3 gw3(512 / 32, 512 / 32, 2);
    wconv_pair_k<<<gw3, 256, 0, stream>>>(W3l, W3r, WT, 512, 512, 512,
                                          nullptr, nullptr, nullptr, nullptr, nullptr, 0.f);
    dim3 g(1024 / 128, (n + 127) / 128);
    gemm_bf16_k<<<g, 256, 0, stream>>>(Abf, WT, xlb, xrb, nullptr, n, 512, 512);
  }
  gat_edge_k<1><<<(n + 3) / 4, 256, 0, stream>>>(xlb, xrb, a3, b3, csr, offsets, hb, n, 0);
  {
    dim3 g(512 / 256, 160);
    col_stats_bf_k<<<g, 256, 0, stream>>>(hb, n, 512, s1_3, s2_3);
    bn_apply8_k<<<(int)(((size_t)n * 512 / 8 + 255) / 256), 256, 0, stream>>>(
        hb, s1_3, s2_3, bn3_g, bn3_b, Abf, (size_t)n * 512, 512, invM);
  }

  // ---- Layer 4 (K=512 -> N=1024 combined), relu fused into edge kernel ----
  {
    dim3 gw4(512 / 32, 512 / 32, 2);
    wconv_pair_k<<<gw4, 256, 0, stream>>>(W4l, W4r, WT, 512, 512, 512,
                                          nullptr, nullptr, nullptr, nullptr, nullptr, 0.f);
    dim3 g(1024 / 128, (n + 127) / 128);
    gemm_bf16_k<<<g, 256, 0, stream>>>(Abf, WT, xlb, xrb, nullptr, n, 512, 512);
  }
  gat_edge_k<1><<<(n + 3) / 4, 256, 0, stream>>>(xlb, xrb, a4, b4, csr, offsets, hb, n, 1);

  // ---- fused head + gather (train rows only) ----
  head_gather_k<<<(NT + 3) / 4, 256, 0, stream>>>(hb, Wh, bh, y, tidx, out, NT);
}

// Round 8
// 829.791 us; speedup vs baseline: 1.0170x; 1.0170x over previous
//
#include <hip/hip_runtime.h>
#include <math.h>

typedef __bf16 bf16x8 __attribute__((ext_vector_type(8)));
typedef float f32x16 __attribute__((ext_vector_type(16)));
typedef unsigned short ushort8 __attribute__((ext_vector_type(8)));

__device__ __forceinline__ float bf2f(unsigned short u) {
  union { unsigned int i; float f; } c; c.i = ((unsigned int)u) << 16; return c.f;
}
__device__ __forceinline__ unsigned short f2bf(float f) {
  union { float f; unsigned int i; } c; c.f = f;
  unsigned int r = (c.i + 0x7fffu + ((c.i >> 16) & 1u)) >> 16;
  return (unsigned short)r;
}

// ---------------- init: zero all stat/bias buffers, deg = 1 (self loop) ----------------
__global__ void zero_k(float* __restrict__ statz, int nz, int* __restrict__ deg, int n) {
  int i = blockIdx.x * blockDim.x + threadIdx.x;
  if (i < nz) statz[i] = 0.f;
  if (i < n) deg[i] = 1;
}

__global__ void deg_count_k(const int* __restrict__ dst, int* __restrict__ deg, int e) {
  int i = blockIdx.x * blockDim.x + threadIdx.x;
  if (i < e) atomicAdd(&deg[dst[i]], 1);
}

__global__ void scan_k(const int* __restrict__ deg, int* __restrict__ offsets,
                       int* __restrict__ cursor, int n) {
  __shared__ int sums[1024];
  int tid = threadIdx.x;
  int chunk = (n + 1023) >> 10;
  int base = tid * chunk;
  int s = 0;
  for (int i = 0; i < chunk; ++i) {
    int j = base + i;
    if (j < n) s += deg[j];
  }
  sums[tid] = s;
  __syncthreads();
  for (int off = 1; off < 1024; off <<= 1) {
    int v = (tid >= off) ? sums[tid - off] : 0;
    __syncthreads();
    sums[tid] += v;
    __syncthreads();
  }
  int run = sums[tid] - s;
  for (int i = 0; i < chunk; ++i) {
    int j = base + i;
    if (j < n) {
      offsets[j] = run;
      cursor[j] = run;
      run += deg[j];
    }
  }
  if (tid == 1023) offsets[n] = sums[1023];
}

__global__ void csr_fill_k(const int* __restrict__ src, const int* __restrict__ dst,
                           int* __restrict__ cursor, int* __restrict__ csr_src,
                           int e, int n) {
  int i = blockIdx.x * blockDim.x + threadIdx.x;
  if (i >= e + n) return;
  int s, d;
  if (i < e) { s = src[i]; d = dst[i]; }
  else       { s = i - e;  d = s; }
  int pos = atomicAdd(&cursor[d], 1);
  csr_src[pos] = s;
}

// ---------------- fused BN0 stats + fp32->bf16 raw convert (coalesced) ----
__global__ __launch_bounds__(256)
void stats_convert_k(const float* __restrict__ x, unsigned short* __restrict__ Abf,
                     float* __restrict__ s1, float* __restrict__ s2,
                     int M, int K, int Kp) {
  int c = blockIdx.x * 256 + threadIdx.x;
  if (c >= Kp) return;
  int rows = (M + gridDim.y - 1) / gridDim.y;
  int r0 = blockIdx.y * rows;
  int r1 = min(M, r0 + rows);
  if (c >= K) {  // zero pad columns
    for (int r = r0; r < r1; ++r) Abf[(size_t)r * Kp + c] = 0;
    return;
  }
  float a = 0.f, b = 0.f;
  int r = r0;
  for (; r + 4 <= r1; r += 4) {
    float v0 = x[(size_t)(r + 0) * K + c];
    float v1 = x[(size_t)(r + 1) * K + c];
    float v2 = x[(size_t)(r + 2) * K + c];
    float v3 = x[(size_t)(r + 3) * K + c];
    a += v0 + v1 + v2 + v3;
    b += v0 * v0 + v1 * v1 + v2 * v2 + v3 * v3;
    Abf[(size_t)(r + 0) * Kp + c] = f2bf(v0);
    Abf[(size_t)(r + 1) * Kp + c] = f2bf(v1);
    Abf[(size_t)(r + 2) * Kp + c] = f2bf(v2);
    Abf[(size_t)(r + 3) * Kp + c] = f2bf(v3);
  }
  for (; r < r1; ++r) {
    float v = x[(size_t)r * K + c];
    a += v; b += v * v;
    Abf[(size_t)r * Kp + c] = f2bf(v);
  }
  atomicAdd(&s1[c], a);
  atomicAdd(&s2[c], b);
}

// ---------------- bf16 column stats ----------------
__global__ __launch_bounds__(256)
void col_stats_bf_k(const unsigned short* __restrict__ h, int M, int D,
                    float* __restrict__ s1, float* __restrict__ s2) {
  int c = blockIdx.x * 256 + threadIdx.x;
  if (c >= D) return;
  int rows = (M + gridDim.y - 1) / gridDim.y;
  int r0 = blockIdx.y * rows;
  int r1 = min(M, r0 + rows);
  float a = 0.f, b = 0.f;
  int r = r0;
  for (; r + 4 <= r1; r += 4) {
    float v0 = bf2f(h[(size_t)(r + 0) * D + c]);
    float v1 = bf2f(h[(size_t)(r + 1) * D + c]);
    float v2 = bf2f(h[(size_t)(r + 2) * D + c]);
    float v3 = bf2f(h[(size_t)(r + 3) * D + c]);
    a += v0 + v1 + v2 + v3;
    b += v0 * v0 + v1 * v1 + v2 * v2 + v3 * v3;
  }
  for (; r < r1; ++r) {
    float v = bf2f(h[(size_t)r * D + c]);
    a += v; b += v * v;
  }
  atomicAdd(&s1[c], a);
  atomicAdd(&s2[c], b);
}

// BN finalize + apply + ReLU fused, bf16 -> bf16, ushort8 vectorized
__global__ __launch_bounds__(256)
void bn_apply8_k(const unsigned short* __restrict__ h,
                 const float* __restrict__ s1, const float* __restrict__ s2,
                 const float* __restrict__ g, const float* __restrict__ b,
                 unsigned short* __restrict__ outb,
                 size_t total, int D, float invM) {
  size_t i = ((size_t)blockIdx.x * 256 + threadIdx.x) * 8;
  if (i >= total) return;
  ushort8 u = *(const ushort8*)(h + i);
  int c = (int)(i % (size_t)D);
  ushort8 o;
#pragma unroll
  for (int j = 0; j < 8; ++j) {
    float m = s1[c + j] * invM;
    float var = fmaxf(s2[c + j] * invM - m * m, 0.f);
    float a = rsqrtf(var + 1e-5f) * g[c + j];
    float cc = b[c + j] - m * a;
    float v = bf2f(u[j]) * a + cc;
    o[j] = f2bf(fmaxf(v, 0.f));
  }
  *(ushort8*)(outb + i) = o;
}

// weight transpose-convert for an l/r PAIR via blockIdx.z:
// W [K,N] fp32 -> WT[z*N .. ][N,Kp] bf16, zero pad.
// BN0-fold mode (s1 != nullptr): row k scaled by a[k]=rsqrt(var)*g, and
// bias[n] += sum_k c[k]*W[k,n] with c[k]=b[k]-m[k]*a[k] (computed inline from s1/s2).
__global__ __launch_bounds__(256)
void wconv_pair_k(const float* __restrict__ Wl, const float* __restrict__ Wr,
                  unsigned short* __restrict__ WT, int K, int N, int Kp,
                  const float* __restrict__ s1, const float* __restrict__ s2,
                  const float* __restrict__ gg, const float* __restrict__ bb,
                  float* __restrict__ bias, float invM) {
  const float* W = blockIdx.z ? Wr : Wl;
  unsigned short* WTo = WT + (size_t)blockIdx.z * N * Kp;
  __shared__ float t[32][33];
  int n0 = blockIdx.x * 32, k0 = blockIdx.y * 32;
  int tx = threadIdx.x & 31, ty = threadIdx.x >> 5;  // 32 x 8
  float bsum = 0.f;
#pragma unroll
  for (int i = 0; i < 32; i += 8) {
    int k = k0 + ty + i, nn = n0 + tx;
    float v = (k < K && nn < N) ? W[(size_t)k * N + nn] : 0.f;
    t[ty + i][tx] = v;
    if (s1 && k < K) {
      float m = s1[k] * invM;
      float var = fmaxf(s2[k] * invM - m * m, 0.f);
      float a = rsqrtf(var + 1e-5f) * gg[k];
      float c = bb[k] - m * a;
      bsum += c * v;
    }
  }
  if (s1) atomicAdd(&bias[blockIdx.z * N + n0 + tx], bsum);
  float ascale = 1.f;
  if (s1) {
    int k = k0 + tx;
    if (k < K) {
      float m = s1[k] * invM;
      float var = fmaxf(s2[k] * invM - m * m, 0.f);
      ascale = rsqrtf(var + 1e-5f) * gg[k];
    }
  }
  __syncthreads();
#pragma unroll
  for (int i = 0; i < 32; i += 8) {
    int nn = n0 + ty + i, k = k0 + tx;
    if (nn < N && k < Kp) {
      float v = t[tx][ty + i] * ascale;
      WTo[(size_t)nn * Kp + k] = f2bf(v);
    }
  }
}

// ---------------- bf16 MFMA GEMM (32x32x16): C = A[M,K] @ Bt[Ntot,K]^T (+bias) -------
// 128x128 tile, BK=64, 4 waves 2x2, each wave 2x2 frags of 32x32x16 over 4 K-steps.
// A/B frag: elem j of lane -> [m|n = lane&31][k = (lane>>5)*8 + j] (within K-step of 16).
// C/D frag: col = lane&31, row = (reg&3) + 8*(reg>>2) + 4*(lane>>5)   [m74/m101]
__global__ __launch_bounds__(256)
void gemm_bf16_k(const unsigned short* __restrict__ A,
                 const unsigned short* __restrict__ Bt,
                 unsigned short* __restrict__ outL, unsigned short* __restrict__ outR,
                 const float* __restrict__ bias, int M, int Nh, int K) {
  __shared__ unsigned short sA[128 * 64];
  __shared__ unsigned short sB[128 * 64];
  const int tid = threadIdx.x;
  const int wave = tid >> 6, lane = tid & 63;
  const int wm = wave >> 1, wn = wave & 1;
  const int l32 = lane & 31, lh = lane >> 5;
  const int row0 = blockIdx.y * 128, col0 = blockIdx.x * 128;

  f32x16 acc[2][2] = {};

  for (int kt = 0; kt < K; kt += 64) {
#pragma unroll
    for (int i = 0; i < 4; ++i) {
      int s = i * 256 + tid;
      int r = s >> 3;
      int g = (s & 7) ^ (r & 7);
      int ra = row0 + r;
      ra = ra < M ? ra : M - 1;
      const unsigned short* ga = A + (size_t)ra * K + (kt + g * 8);
      __builtin_amdgcn_global_load_lds(
          (const __attribute__((address_space(1))) void*)ga,
          (__attribute__((address_space(3))) void*)&sA[s * 8], 16, 0, 0);
      const unsigned short* gb = Bt + (size_t)(col0 + r) * K + (kt + g * 8);
      __builtin_amdgcn_global_load_lds(
          (const __attribute__((address_space(1))) void*)gb,
          (__attribute__((address_space(3))) void*)&sB[s * 8], 16, 0, 0);
    }
    __syncthreads();
#pragma unroll
    for (int s = 0; s < 4; ++s) {          // 4 K-steps of 16
      int g = s * 2 + lh;                   // granule index 0..7
      bf16x8 af[2], bfr[2];
#pragma unroll
      for (int t = 0; t < 2; ++t) {
        int r = wm * 64 + t * 32 + l32;
        af[t] = *(const bf16x8*)&sA[(r * 8 + (g ^ (r & 7))) * 8];
        int rb = wn * 64 + t * 32 + l32;
        bfr[t] = *(const bf16x8*)&sB[(rb * 8 + (g ^ (rb & 7))) * 8];
      }
#pragma unroll
      for (int mt = 0; mt < 2; ++mt)
#pragma unroll
        for (int nt = 0; nt < 2; ++nt)
          acc[mt][nt] = __builtin_amdgcn_mfma_f32_32x32x16_bf16(af[mt], bfr[nt], acc[mt][nt], 0, 0, 0);
    }
    __syncthreads();
  }
#pragma unroll
  for (int mt = 0; mt < 2; ++mt) {
#pragma unroll
    for (int nt = 0; nt < 2; ++nt) {
      int col = col0 + wn * 64 + nt * 32 + l32;
      float bv = bias ? bias[col] : 0.f;
      unsigned short* base;
      int cc;
      if (col < Nh) { base = outL; cc = col; }
      else          { base = outR; cc = col - Nh; }
      int rb0 = row0 + wm * 64 + mt * 32 + 4 * lh;
#pragma unroll
      for (int r = 0; r < 16; ++r) {
        int rr = rb0 + (r & 3) + 8 * (r >> 2);
        if (rr < M) base[(size_t)rr * Nh + cc] = f2bf(acc[mt][nt][r] + bv);
      }
    }
  }
}

// ---------------- Fused GATv2 edge kernel, depth-3 pipelined gathers ----------------
template <int H>
__global__ __launch_bounds__(256)
void gat_edge_k(const unsigned short* __restrict__ xl, const unsigned short* __restrict__ xr,
                const float* __restrict__ att, const float* __restrict__ bias,
                const int* __restrict__ csr, const int* __restrict__ offsets,
                unsigned short* __restrict__ out, int n, int relu) {
  int gw = (blockIdx.x * 256 + threadIdx.x) >> 6;
  int lane = threadIdx.x & 63;
  if (gw >= n * H) return;
  int node, head;
  if (H == 1) { node = gw; head = 0; }
  else        { node = gw >> 1; head = gw & 1; }
  const int W = H * 512;
  const size_t rowoff = (size_t)node * W + head * 512;
  const size_t choff = (size_t)head * 512 + (size_t)(lane * 8);

  float xrv[8], atv[8];
  {
    ushort8 u = *(const ushort8*)(xr + rowoff + lane * 8);
    const float* ap = att + head * 512 + lane * 8;
#pragma unroll
    for (int j = 0; j < 8; ++j) { xrv[j] = bf2f(u[j]); atv[j] = ap[j]; }
  }
  int p0 = offsets[node], p1 = offsets[node + 1];
  ushort8 u0 = *(const ushort8*)(xl + (size_t)csr[p0] * W + choff);
  ushort8 u1 = u0, u2 = u0;
  if (p0 + 1 < p1) u1 = *(const ushort8*)(xl + (size_t)csr[p0 + 1] * W + choff);
  if (p0 + 2 < p1) u2 = *(const ushort8*)(xl + (size_t)csr[p0 + 2] * W + choff);

  float m = -1e30f, l = 0.f;
  float acc[8];
#pragma unroll
  for (int j = 0; j < 8; ++j) acc[j] = 0.f;
  for (int p = p0; p < p1; ++p) {
    ushort8 u = u0;
    u0 = u1; u1 = u2;
    if (p + 3 < p1) u2 = *(const ushort8*)(xl + (size_t)csr[p + 3] * W + choff);
    float lv[8];
    float e = 0.f;
#pragma unroll
    for (int j = 0; j < 8; ++j) {
      lv[j] = bf2f(u[j]);
      float z = lv[j] + xrv[j];
      z = fmaxf(z, 0.f) + 0.2f * fminf(z, 0.f);
      e = fmaf(z, atv[j], e);
    }
#pragma unroll
    for (int off = 32; off > 0; off >>= 1) e += __shfl_xor(e, off, 64);
    float mn = fmaxf(m, e);
    float corr = __expf(m - mn);
    float w = __expf(e - mn);
    l = l * corr + w;
#pragma unroll
    for (int j = 0; j < 8; ++j) acc[j] = acc[j] * corr + w * lv[j];
    m = mn;
  }
  float inv = 1.f / (l * (float)(p1 - p0));
  const float* bp = bias + head * 512 + lane * 8;
  ushort8 o;
#pragma unroll
  for (int j = 0; j < 8; ++j) {
    float v = acc[j] * inv + bp[j];
    if (relu) v = fmaxf(v, 0.f);
    o[j] = f2bf(v);
  }
  *(ushort8*)(out + rowoff + lane * 8) = o;
}

// ---------------- fused head + gather: out = sigmoid(h[tidx]@Wh+bh), y[tidx] --------
__global__ __launch_bounds__(256)
void head_gather_k(const unsigned short* __restrict__ h, const float* __restrict__ Wh,
                   const float* __restrict__ bh, const float* __restrict__ y,
                   const int* __restrict__ tidx, float* __restrict__ out, int nt) {
  int gw = (blockIdx.x * 256 + threadIdx.x) >> 6;
  int lane = threadIdx.x & 63;
  if (gw >= nt) return;
  int j = tidx[gw];
  ushort8 u = *(const ushort8*)(h + (size_t)j * 512 + lane * 8);
  const float* wp = Wh + lane * 8;
  float s = 0.f;
#pragma unroll
  for (int q = 0; q < 8; ++q) s = fmaf(bf2f(u[q]), wp[q], s);
#pragma unroll
  for (int off = 32; off > 0; off >>= 1) s += __shfl_xor(s, off, 64);
  if (lane == 0) {
    out[gw] = 1.f / (1.f + __expf(-(s + bh[0])));
    out[nt + gw] = y[j];
  }
}

// ---------------- launch ----------------
extern "C" void kernel_launch(void* const* d_in, const int* in_sizes, int n_in,
                              void* d_out, int out_size, void* d_ws, size_t ws_size,
                              hipStream_t stream) {
  const float* x     = (const float*)d_in[0];
  const int*   ei    = (const int*)d_in[1];
  const float* y     = (const float*)d_in[2];
  const int*   tidx  = (const int*)d_in[3];
  const float* bn0_g = (const float*)d_in[4];
  const float* bn0_b = (const float*)d_in[5];
  const float* W1l   = (const float*)d_in[6];
  const float* W1r   = (const float*)d_in[7];
  const float* a1    = (const float*)d_in[8];
  const float* b1    = (const float*)d_in[9];
  const float* bn1_g = (const float*)d_in[10];
  const float* bn1_b = (const float*)d_in[11];
  const float* W2l   = (const float*)d_in[12];
  const float* W2r   = (const float*)d_in[13];
  const float* a2    = (const float*)d_in[14];
  const float* b2    = (const float*)d_in[15];
  const float* bn2_g = (const float*)d_in[16];
  const float* bn2_b = (const float*)d_in[17];
  const float* W3l   = (const float*)d_in[18];
  const float* W3r   = (const float*)d_in[19];
  const float* a3    = (const float*)d_in[20];
  const float* b3    = (const float*)d_in[21];
  const float* bn3_g = (const float*)d_in[22];
  const float* bn3_b = (const float*)d_in[23];
  const float* W4l   = (const float*)d_in[24];
  const float* W4r   = (const float*)d_in[25];
  const float* a4    = (const float*)d_in[26];
  const float* b4    = (const float*)d_in[27];
  const float* Wh    = (const float*)d_in[28];
  const float* bh    = (const float*)d_in[29];
  float* out = (float*)d_out;

  const int n   = in_sizes[2];      // 8000
  const int E   = in_sizes[1] / 2;  // 64000
  const int FIN = in_sizes[4];      // 3201
  const int NT  = in_sizes[3];      // 4000
  const int ET  = E + n;
  const int KP1 = 3264;

  // ---- workspace layout ----
  unsigned short* us = (unsigned short*)d_ws;
  const size_t ABF_SZ = (size_t)n * KP1;
  unsigned short* Abf = us;
  unsigned short* hb  = us + ABF_SZ;
  unsigned short* xlb = hb + (size_t)n * 1024;
  unsigned short* xrb = xlb + (size_t)n * 1024;
  float* fp = (float*)(xrb + (size_t)n * 1024);
  float* s1_0  = fp;           fp += 3328;
  float* s2_0  = fp;           fp += 3328;
  float* s1_1  = fp;           fp += 1024;
  float* s2_1  = fp;           fp += 1024;
  float* s1_2  = fp;           fp += 1024;
  float* s2_2  = fp;           fp += 1024;
  float* s1_3  = fp;           fp += 1024;
  float* s2_3  = fp;           fp += 1024;
  float* biasb = fp;           fp += 2048;
  const int kZeroCount = 14848;
  int* deg     = (int*)fp;
  int* offsets = deg + n;
  int* cursor  = offsets + n + 1;
  int* csr     = cursor + n;
  unsigned short* W1T = hb;                          // [2048, KP1] combined Bt
  unsigned short* WT  = Abf + (size_t)n * 1024;      // layers 2-4 combined Bt

  // ---- init + CSR build ----
  zero_k<<<(kZeroCount + 255) / 256, 256, 0, stream>>>(s1_0, kZeroCount, deg, n);
  deg_count_k<<<(E + 255) / 256, 256, 0, stream>>>(ei + E, deg, E);
  scan_k<<<1, 1024, 0, stream>>>(deg, offsets, cursor, n);
  csr_fill_k<<<(ET + 255) / 256, 256, 0, stream>>>(ei, ei + E, cursor, csr, E, n);

  float invM = 1.f / (float)n;

  // ---- BN0: fused stats + raw bf16 convert (single coalesced pass over x) ----
  {
    dim3 g((KP1 + 255) / 256, 200);
    stats_convert_k<<<g, 256, 0, stream>>>(x, Abf, s1_0, s2_0, n, FIN, KP1);
  }

  // ---- Layer 1 (H=2, K=3264 -> 2 x N=1024), BN0 folded into weights ----
  {
    dim3 gw1(1024 / 32, KP1 / 32, 2);
    wconv_pair_k<<<gw1, 256, 0, stream>>>(W1l, W1r, W1T, FIN, 1024, KP1,
                                          s1_0, s2_0, bn0_g, bn0_b, biasb, invM);
    dim3 g(1024 / 128, (n + 127) / 128);
    gemm_bf16_k<<<g, 256, 0, stream>>>(Abf, W1T, xlb, xlb, biasb, n, 1024, KP1);
    gemm_bf16_k<<<g, 256, 0, stream>>>(Abf, W1T + (size_t)1024 * KP1, xrb, xrb,
                                       biasb + 1024, n, 1024, KP1);
  }
  gat_edge_k<2><<<(n * 2 + 3) / 4, 256, 0, stream>>>(xlb, xrb, a1, b1, csr, offsets, hb, n, 0);
  {
    dim3 g(1024 / 256, 160);
    col_stats_bf_k<<<g, 256, 0, stream>>>(hb, n, 1024, s1_1, s2_1);
    bn_apply8_k<<<(int)(((size_t)n * 1024 / 8 + 255) / 256), 256, 0, stream>>>(
        hb, s1_1, s2_1, bn1_g, bn1_b, Abf, (size_t)n * 1024, 1024, invM);
  }

  // ---- Layer 2 (K=1024 -> N=1024 combined) ----
  {
    dim3 gw2(512 / 32, 1024 / 32, 2);
    wconv_pair_k<<<gw2, 256, 0, stream>>>(W2l, W2r, WT, 1024, 512, 1024,
                                          nullptr, nullptr, nullptr, nullptr, nullptr, 0.f);
    dim3 g(1024 / 128, (n + 127) / 128);
    gemm_bf16_k<<<g, 256, 0, stream>>>(Abf, WT, xlb, xrb, nullptr, n, 512, 1024);
  }
  gat_edge_k<1><<<(n + 3) / 4, 256, 0, stream>>>(xlb, xrb, a2, b2, csr, offsets, hb, n, 0);
  {
    dim3 g(512 / 256, 160);
    col_stats_bf_k<<<g, 256, 0, stream>>>(hb, n, 512, s1_2, s2_2);
    bn_apply8_k<<<(int)(((size_t)n * 512 / 8 + 255) / 256), 256, 0, stream>>>(
        hb, s1_2, s2_2, bn2_g, bn2_b, Abf, (size_t)n * 512, 512, invM);
  }

  // ---- Layer 3 (K=512 -> N=1024 combined) ----
  {
    dim3 gw3(512 / 32, 512 / 32, 2);
    wconv_pair_k<<<gw3, 256, 0, stream>>>(W3l, W3r, WT, 512, 512, 512,
                                          nullptr, nullptr, nullptr, nullptr, nullptr, 0.f);
    dim3 g(1024 / 128, (n + 127) / 128);
    gemm_bf16_k<<<g, 256, 0, stream>>>(Abf, WT, xlb, xrb, nullptr, n, 512, 512);
  }
  gat_edge_k<1><<<(n + 3) / 4, 256, 0, stream>>>(xlb, xrb, a3, b3, csr, offsets, hb, n, 0);
  {
    dim3 g(512 / 256, 160);
    col_stats_bf_k<<<g, 256, 0, stream>>>(hb, n, 512, s1_3, s2_3);
    bn_apply8_k<<<(int)(((size_t)n * 512 / 8 + 255) / 256), 256, 0, stream>>>(
        hb, s1_3, s2_3, bn3_g, bn3_b, Abf, (size_t)n * 512, 512, invM);
  }

  // ---- Layer 4 (K=512 -> N=1024 combined), relu fused into edge kernel ----
  {
    dim3 gw4(512 / 32, 512 / 32, 2);
    wconv_pair_k<<<gw4, 256, 0, stream>>>(W4l, W4r, WT, 512, 512, 512,
                                          nullptr, nullptr, nullptr, nullptr, nullptr, 0.f);
    dim3 g(1024 / 128, (n + 127) / 128);
    gemm_bf16_k<<<g, 256, 0, stream>>>(Abf, WT, xlb, xrb, nullptr, n, 512, 512);
  }
  gat_edge_k<1><<<(n + 3) / 4, 256, 0, stream>>>(xlb, xrb, a4, b4, csr, offsets, hb, n, 1);

  // ---- fused head + gather (train rows only) ----
  head_gather_k<<<(NT + 3) / 4, 256, 0, stream>>>(hb, Wh, bh, y, tidx, out, NT);
}